// Round 6
// baseline (346.061 us; speedup 1.0000x reference)
//
#include <hip/hip_runtime.h>
#include <hip/hip_bf16.h>
#include <math.h>

typedef __bf16 bf16x8 __attribute__((ext_vector_type(8)));
typedef float floatx4 __attribute__((ext_vector_type(4)));

#define ATT_SCALE 0.35355339059327373f  // DH^-0.5, DH=8

__device__ __forceinline__ __bf16 f2b(float x) { return (__bf16)x; }

// ---------------------------------------------------------------------------
// K1: Q = p@wq, Ks = (p@wk)*SCALE, V = p@wv. 256 blocks x 256 thr, 8 rows/blk.
// ---------------------------------------------------------------------------
__global__ __launch_bounds__(256) void k_proj(const float* __restrict__ p,
                       const float* __restrict__ wq, const float* __restrict__ wk,
                       const float* __restrict__ wv,
                       float* __restrict__ Q, float* __restrict__ Ks,
                       float* __restrict__ V) {
  int blk = blockIdx.x, t = threadIdx.x;
  __shared__ float xr[8][64];
  {
    int rr = t >> 5, cc = (t & 31) * 2;
    float2 pz = *reinterpret_cast<const float2*>(p + blk * 512 + rr * 64 + cc);
    xr[rr][cc] = pz.x; xr[rr][cc + 1] = pz.y;
  }
  __syncthreads();
  if (t < 192) {
    int mat = t >> 6, c = t & 63;
    const float* w = (mat == 0) ? wq : ((mat == 1) ? wk : wv);
    float acc[8] = {0.f, 0.f, 0.f, 0.f, 0.f, 0.f, 0.f, 0.f};
#pragma unroll 8
    for (int k = 0; k < 64; k++) {
      float wv_ = w[k * 64 + c];
#pragma unroll
      for (int r = 0; r < 8; r++) acc[r] += xr[r][k] * wv_;
    }
    float* dst = (mat == 0) ? Q : ((mat == 1) ? Ks : V);
    float sc = (mat == 1) ? ATT_SCALE : 1.f;
#pragma unroll
    for (int r = 0; r < 8; r++) dst[(blk * 8 + r) * 64 + c] = acc[r] * sc;
  }
}

// ---------------------------------------------------------------------------
// K2: edge attention — byte-identical to the round-2 version (≈HBM floor).
// ---------------------------------------------------------------------------
__global__ __launch_bounds__(256) void k_edge(
    const float* __restrict__ e, const float* __restrict__ we,
    const float* __restrict__ krw, const float* __restrict__ mask,
    const float* __restrict__ hin, const float* __restrict__ pin,
    const float* __restrict__ wo, const float* __restrict__ cq_wkv,
    const float* __restrict__ Q, const float* __restrict__ Ks,
    const float* __restrict__ V, float* __restrict__ Kc, float* __restrict__ Vc) {
  int bi = blockIdx.x;          // b*256 + i
  int b = bi >> 8;
  int t = threadIdx.x;
  int w = t >> 6, l = t & 63;
  int l15 = l & 15, quad = l >> 4, half8 = (l >> 3) & 1, d = l & 7;

  bf16x8 wfrag[4][2];
  for (int nt = 0; nt < 4; nt++)
    for (int kc = 0; kc < 2; kc++)
      for (int jj = 0; jj < 8; jj++)
        wfrag[nt][kc][jj] = f2b(we[(kc * 32 + quad * 8 + jj) * 64 + nt * 16 + l15]);

  float qv[4];
  for (int nt = 0; nt < 4; nt++) qv[nt] = Q[bi * 64 + nt * 16 + l15];
  float mi = mask[bi];

  float aout[4] = {0.f, 0.f, 0.f, 0.f};
  float aden[4] = {0.f, 0.f, 0.f, 0.f};

  for (int mt = 0; mt < 4; mt++) {
    int j0 = w * 64 + mt * 16;
    const float* ep = e + ((long)bi * 256 + j0 + l15) * 64 + quad * 8;
    float4 ea = *reinterpret_cast<const float4*>(ep);
    float4 eb4 = *reinterpret_cast<const float4*>(ep + 4);
    float4 ec = *reinterpret_cast<const float4*>(ep + 32);
    float4 ed4 = *reinterpret_cast<const float4*>(ep + 36);
    bf16x8 a0, a1;
    a0[0] = f2b(ea.x); a0[1] = f2b(ea.y); a0[2] = f2b(ea.z); a0[3] = f2b(ea.w);
    a0[4] = f2b(eb4.x); a0[5] = f2b(eb4.y); a0[6] = f2b(eb4.z); a0[7] = f2b(eb4.w);
    a1[0] = f2b(ec.x); a1[1] = f2b(ec.y); a1[2] = f2b(ec.z); a1[3] = f2b(ec.w);
    a1[4] = f2b(ed4.x); a1[5] = f2b(ed4.y); a1[6] = f2b(ed4.z); a1[7] = f2b(ed4.w);

    int jr0 = j0 + quad * 4;
    float krw_r[4], mj_r[4];
    for (int r = 0; r < 4; r++) {
      krw_r[r] = krw[(long)bi * 256 + jr0 + r];
      mj_r[r] = mask[b * 256 + jr0 + r];
    }
    for (int nt = 0; nt < 4; nt++) {
      floatx4 acc = {0.f, 0.f, 0.f, 0.f};
      acc = __builtin_amdgcn_mfma_f32_16x16x32_bf16(a0, wfrag[nt][0], acc, 0, 0, 0);
      acc = __builtin_amdgcn_mfma_f32_16x16x32_bf16(a1, wfrag[nt][1], acc, 0, 0, 0);
      int hk = nt * 16 + l15;
      int hbase = hk & 56;
      for (int r = 0; r < 4; r++) {
        int jr = jr0 + r;
        float s = acc[r] * qv[nt] * Ks[(b * 256 + jr) * 64 + hk];
        s += __shfl_xor(s, 1);
        s += __shfl_xor(s, 2);
        s += __shfl_xor(s, 4);
        float wg = __expf(s) * krw_r[r] * mj_r[r];
        aden[nt] += wg;
        aout[nt] += wg * V[(b * 256 + jr) * 64 + hbase + d];
      }
    }
  }
  for (int nt = 0; nt < 4; nt++) {
    float o = aout[nt], dn = aden[nt];
    o += __shfl_xor(o, 16); o += __shfl_xor(o, 32);
    dn += __shfl_xor(dn, 16); dn += __shfl_xor(dn, 32);
    aout[nt] = o; aden[nt] = dn;
  }

  __shared__ float red[4][64];
  __shared__ float redden[4][8];
  __shared__ float pav[64];
  __shared__ float hcl[64];
  if (l < 16) {
    for (int nt = 0; nt < 4; nt++) {
      int head = nt * 2 + half8;
      red[w][head * 8 + d] = aout[nt];
      if (d == 0) redden[w][head] = aden[nt];
    }
  }
  __syncthreads();
  if (t < 64) {
    int head = t >> 3;
    float num = red[0][t] + red[1][t] + red[2][t] + red[3][t];
    float den = redden[0][head] + redden[1][head] + redden[2][head] + redden[3][head];
    num *= mi;
    den = fmaxf(den * mi, 1e-6f);
    pav[t] = num / den;
  }
  __syncthreads();
  if (t < 64) {
    float a = 0.f;
    for (int c = 0; c < 64; c++) a += pav[c] * wo[c * 64 + t];
    hcl[t] = hin[bi * 64 + t] + pin[bi * 64 + t] + tanhf(a);
  }
  __syncthreads();
  if (t < 128) {
    float a = 0.f;
    for (int c = 0; c < 64; c++) a += hcl[c] * cq_wkv[c * 128 + t];
    if (t < 64) Kc[bi * 64 + t] = a;
    else        Vc[bi * 64 + t - 64] = a;
  }
}

// ---------------------------------------------------------------------------
// Weight staging: global fp32 [NR x NC] -> LDS bf16 [NR x ST], 1024 threads.
// ---------------------------------------------------------------------------
template <int NR, int NC, int ST>
__device__ __forceinline__ void stage_w(const float* __restrict__ g,
                                        __bf16* wls, int t) {
  constexpr int PER = (NR * NC) >> 10;   // 4 or 8 floats per thread
  int i0 = t * PER;
  int k = i0 / NC, c0 = i0 % NC;
  const float* src = g + k * NC + c0;
  __bf16* dst = wls + k * ST + c0;
#pragma unroll
  for (int m = 0; m < PER; m += 4) {
    float4 v = *reinterpret_cast<const float4*>(src + m);
    dst[m] = f2b(v.x); dst[m + 1] = f2b(v.y);
    dst[m + 2] = f2b(v.z); dst[m + 3] = f2b(v.w);
  }
}

// ---------------------------------------------------------------------------
// K3: fused latent tail, 8 blocks x 1024 threads.
// Attention phases use 4-rows-per-thread mapping (rg8 x h8 x s16) to cut
// K/V LDS read amplification 4x. LDS ~61 KB.
// ---------------------------------------------------------------------------
__global__ __launch_bounds__(1024) void k_tail(
    const float* __restrict__ quer, const float* __restrict__ Kc,
    const float* __restrict__ Vc, const float* __restrict__ mask,
    const float* __restrict__ cq_wq, const float* __restrict__ cq_wo,
    const float* __restrict__ cq_bo,
    const float* __restrict__ sa_wq, const float* __restrict__ sa_wkv,
    const float* __restrict__ sa_wo, const float* __restrict__ sa_bo,
    const float* __restrict__ oq_w, const float* __restrict__ g1,
    const float* __restrict__ b1, const float* __restrict__ w1,
    const float* __restrict__ w2, const float* __restrict__ g2,
    const float* __restrict__ b2v, float* __restrict__ out) {
  int b = blockIdx.x;
  int t = threadIdx.x;

  __shared__ float sq[32 * 68];   // latent state, fp32
  __shared__ float sx[32 * 68];   // q1/qq/x/y
  __shared__ float pool[6784];    // [0,4608): KV bf16 / selfKV / ffnh ; soc at +4608
  __shared__ float smask[256];
  __shared__ __bf16 wls[8448];    // staged weights (64x66 / 64x130 / 128x66)

  float* soc = pool + 4608;                       // 32*68
  __bf16* kq = reinterpret_cast<__bf16*>(pool);   // [64][72] bf16
  __bf16* vq = kq + 4608;                         // [64][72] bf16

  const int rr6 = t >> 6, c6 = t & 63;            // matmul-64 mapping
  const int rg = t >> 7, h8 = (t >> 4) & 7, s16 = t & 15;  // attention mapping

  // P0: quer -> sq, mask, stage cq_wq
  {
    float2 qz = *reinterpret_cast<const float2*>(quer + b * 2048 + (t >> 5) * 64 + (t & 31) * 2);
    sq[(t >> 5) * 68 + (t & 31) * 2] = qz.x;
    sq[(t >> 5) * 68 + (t & 31) * 2 + 1] = qz.y;
    if (t < 256) smask[t] = mask[b * 256 + t];
    stage_w<64, 64, 66>(cq_wq, wls, t);
  }
  __syncthreads();

  // P1: q1 = quer @ cq_wq -> sx
  {
    float a0 = 0.f, a1 = 0.f;
#pragma unroll 8
    for (int k = 0; k < 64; k++) {
      float wv = (float)wls[k * 66 + c6];
      a0 += sq[rr6 * 68 + k] * wv;
      a1 += sq[(rr6 + 16) * 68 + k] * wv;
    }
    sx[rr6 * 68 + c6] = a0;
    sx[(rr6 + 16) * 68 + c6] = a1;
  }
  __syncthreads();

  // P2: cross-attn. Thread owns rows rg*4..rg*4+3, head h8, j-slice s16.
  {
    float qv8[4][8];
#pragma unroll
    for (int rr = 0; rr < 4; rr++)
#pragma unroll
      for (int dd = 0; dd < 8; dd++)
        qv8[rr][dd] = sx[(rg * 4 + rr) * 68 + h8 * 8 + dd];
    float num[4][8];
    float den[4] = {0.f, 0.f, 0.f, 0.f};
#pragma unroll
    for (int rr = 0; rr < 4; rr++)
#pragma unroll
      for (int dd = 0; dd < 8; dd++) num[rr][dd] = 0.f;

    for (int qtr = 0; qtr < 4; qtr++) {
      {  // stage K/V quarter bf16, row stride 72: 512 thr each, 8 elems/thread
        int half = t >> 9, idx = t & 511;
        int jl = idx >> 3, c0 = (idx & 7) * 8;
        const float* src = (half ? Vc : Kc) + ((long)(b * 256 + qtr * 64 + jl)) * 64 + c0;
        __bf16* dst = (half ? vq : kq) + jl * 72 + c0;
        float4 u = *reinterpret_cast<const float4*>(src);
        float4 v = *reinterpret_cast<const float4*>(src + 4);
        dst[0] = f2b(u.x); dst[1] = f2b(u.y); dst[2] = f2b(u.z); dst[3] = f2b(u.w);
        dst[4] = f2b(v.x); dst[5] = f2b(v.y); dst[6] = f2b(v.z); dst[7] = f2b(v.w);
      }
      if (qtr == 0) stage_w<64, 64, 66>(cq_wo, wls, t);  // prefetch next weights
      __syncthreads();
#pragma unroll
      for (int jj = 0; jj < 4; jj++) {
        int jl = jj * 16 + s16;
        bf16x8 kk = *reinterpret_cast<const bf16x8*>(kq + jl * 72 + h8 * 8);
        bf16x8 vv = *reinterpret_cast<const bf16x8*>(vq + jl * 72 + h8 * 8);
        float kf[8], vf[8];
#pragma unroll
        for (int dd = 0; dd < 8; dd++) { kf[dd] = (float)kk[dd]; vf[dd] = (float)vv[dd]; }
        float msel = smask[qtr * 64 + jl];
#pragma unroll
        for (int rr = 0; rr < 4; rr++) {
          float sc = qv8[rr][0] * kf[0] + qv8[rr][1] * kf[1]
                   + qv8[rr][2] * kf[2] + qv8[rr][3] * kf[3]
                   + qv8[rr][4] * kf[4] + qv8[rr][5] * kf[5]
                   + qv8[rr][6] * kf[6] + qv8[rr][7] * kf[7];
          sc *= ATT_SCALE;
          sc = (msel > 0.5f) ? sc : -1e30f;
          sc = fminf(fmaxf(sc, -5.f), 5.f);
          float ex = __expf(sc);
          den[rr] += ex;
#pragma unroll
          for (int dd = 0; dd < 8; dd++) num[rr][dd] += ex * vf[dd];
        }
      }
      __syncthreads();
    }
    // reduce over s16 (lanes t&15)
#pragma unroll
    for (int rr = 0; rr < 4; rr++) {
      float dn = den[rr];
      dn += __shfl_xor(dn, 1); dn += __shfl_xor(dn, 2);
      dn += __shfl_xor(dn, 4); dn += __shfl_xor(dn, 8);
      den[rr] = dn;
#pragma unroll
      for (int dd = 0; dd < 8; dd++) {
        float v = num[rr][dd];
        v += __shfl_xor(v, 1); v += __shfl_xor(v, 2);
        v += __shfl_xor(v, 4); v += __shfl_xor(v, 8);
        num[rr][dd] = v;
      }
    }
    if (s16 == 0) {
#pragma unroll
      for (int rr = 0; rr < 4; rr++) {
        float inv = 1.f / den[rr];
#pragma unroll
        for (int dd = 0; dd < 8; dd++)
          soc[(rg * 4 + rr) * 68 + h8 * 8 + dd] = num[rr][dd] * inv;
      }
    }
  }
  __syncthreads();

  // P4: q = quer + soc @ cq_wo + cq_bo
  {
    float a0 = 0.f, a1 = 0.f;
#pragma unroll 8
    for (int k = 0; k < 64; k++) {
      float wv = (float)wls[k * 66 + c6];
      a0 += soc[rr6 * 68 + k] * wv;
      a1 += soc[(rr6 + 16) * 68 + k] * wv;
    }
    float bb = cq_bo[c6];
    sq[rr6 * 68 + c6] += a0 + bb;
    sq[(rr6 + 16) * 68 + c6] += a1 + bb;
  }
  __syncthreads();

  // Two latent self-attention layers
  for (int layer = 0; layer < 2; layer++) {
    const float* wql = sa_wq + layer * 4096;
    const float* wkvl = sa_wkv + layer * 8192;
    const float* wol = sa_wo + layer * 4096;
    const float* bol = sa_bo + layer * 64;

    stage_w<64, 64, 66>(wql, wls, t);
    __syncthreads();
    {  // qq = sq @ wql -> sx
      float a0 = 0.f, a1 = 0.f;
#pragma unroll 8
      for (int k = 0; k < 64; k++) {
        float wv = (float)wls[k * 66 + c6];
        a0 += sq[rr6 * 68 + k] * wv;
        a1 += sq[(rr6 + 16) * 68 + k] * wv;
      }
      sx[rr6 * 68 + c6] = a0;
      sx[(rr6 + 16) * 68 + c6] = a1;
    }
    __syncthreads();
    stage_w<64, 128, 130>(wkvl, wls, t);
    __syncthreads();
    {  // selfKV: K -> pool[0..2080), V -> pool[2080..4160), stride 65
      int rrk = t >> 7, ck = t & 127;
      float a0 = 0.f, a1 = 0.f, a2 = 0.f, a3 = 0.f;
#pragma unroll 8
      for (int k = 0; k < 64; k++) {
        float wv = (float)wls[k * 130 + ck];
        a0 += sq[rrk * 68 + k] * wv;
        a1 += sq[(rrk + 8) * 68 + k] * wv;
        a2 += sq[(rrk + 16) * 68 + k] * wv;
        a3 += sq[(rrk + 24) * 68 + k] * wv;
      }
      float* dst = (ck < 64) ? (pool + rrk * 65 + ck) : (pool + 2080 + rrk * 65 + (ck - 64));
      dst[0] = a0; dst[8 * 65] = a1; dst[16 * 65] = a2; dst[24 * 65] = a3;
    }
    __syncthreads();
    {  // self-attn: rows rg*4.., head h8, j = jj*16+s16 (2 j/thread) + prefetch wol
      stage_w<64, 64, 66>(wol, wls, t);
      float qv8[4][8];
#pragma unroll
      for (int rr = 0; rr < 4; rr++)
#pragma unroll
        for (int dd = 0; dd < 8; dd++)
          qv8[rr][dd] = sx[(rg * 4 + rr) * 68 + h8 * 8 + dd];
      float nm[4][8];
      float dn[4] = {0.f, 0.f, 0.f, 0.f};
#pragma unroll
      for (int rr = 0; rr < 4; rr++)
#pragma unroll
        for (int dd = 0; dd < 8; dd++) nm[rr][dd] = 0.f;
#pragma unroll
      for (int jj = 0; jj < 2; jj++) {
        int j = jj * 16 + s16;
        const float* kp = pool + j * 65 + h8 * 8;
        const float* vp = pool + 2080 + j * 65 + h8 * 8;
        float kf[8], vf[8];
#pragma unroll
        for (int dd = 0; dd < 8; dd++) { kf[dd] = kp[dd]; vf[dd] = vp[dd]; }
#pragma unroll
        for (int rr = 0; rr < 4; rr++) {
          float sc = qv8[rr][0] * kf[0] + qv8[rr][1] * kf[1]
                   + qv8[rr][2] * kf[2] + qv8[rr][3] * kf[3]
                   + qv8[rr][4] * kf[4] + qv8[rr][5] * kf[5]
                   + qv8[rr][6] * kf[6] + qv8[rr][7] * kf[7];
          sc *= ATT_SCALE;
          sc = fminf(fmaxf(sc, -5.f), 5.f);
          float ex = __expf(sc);
          dn[rr] += ex;
#pragma unroll
          for (int dd = 0; dd < 8; dd++) nm[rr][dd] += ex * vf[dd];
        }
      }
#pragma unroll
      for (int rr = 0; rr < 4; rr++) {
        float d2 = dn[rr];
        d2 += __shfl_xor(d2, 1); d2 += __shfl_xor(d2, 2);
        d2 += __shfl_xor(d2, 4); d2 += __shfl_xor(d2, 8);
        dn[rr] = d2;
#pragma unroll
        for (int dd = 0; dd < 8; dd++) {
          float v = nm[rr][dd];
          v += __shfl_xor(v, 1); v += __shfl_xor(v, 2);
          v += __shfl_xor(v, 4); v += __shfl_xor(v, 8);
          nm[rr][dd] = v;
        }
      }
      if (s16 == 0) {
#pragma unroll
        for (int rr = 0; rr < 4; rr++) {
          float inv = 1.f / dn[rr];
#pragma unroll
          for (int dd = 0; dd < 8; dd++)
            soc[(rg * 4 + rr) * 68 + h8 * 8 + dd] = nm[rr][dd] * inv;
        }
      }
    }
    __syncthreads();
    {  // q += soc @ wol + bol
      float a0 = 0.f, a1 = 0.f;
#pragma unroll 8
      for (int k = 0; k < 64; k++) {
        float wv = (float)wls[k * 66 + c6];
        a0 += soc[rr6 * 68 + k] * wv;
        a1 += soc[(rr6 + 16) * 68 + k] * wv;
      }
      float bb = bol[c6];
      sq[rr6 * 68 + c6] += a0 + bb;
      sq[(rr6 + 16) * 68 + c6] += a1 + bb;
    }
    __syncthreads();
  }

  // Final: x = q @ oq_w ; LN1 ; ffn ; LN2
  stage_w<64, 64, 66>(oq_w, wls, t);
  __syncthreads();
  {
    float a0 = 0.f, a1 = 0.f;
#pragma unroll 8
    for (int k = 0; k < 64; k++) {
      float wv = (float)wls[k * 66 + c6];
      a0 += sq[rr6 * 68 + k] * wv;
      a1 += sq[(rr6 + 16) * 68 + k] * wv;
    }
    sx[rr6 * 68 + c6] = a0;
    sx[(rr6 + 16) * 68 + c6] = a1;
  }
  __syncthreads();
  {  // LN1 in place (wave-local rows) + stage w1
    int wv_ = t >> 6, lc = t & 63;
#pragma unroll
    for (int pass = 0; pass < 2; pass++) {
      int rr = wv_ + pass * 16;
      float x = sx[rr * 68 + lc];
      float m = x;
      for (int off = 1; off < 64; off <<= 1) m += __shfl_xor(m, off);
      m *= (1.f / 64.f);
      float dv = x - m, vv = dv * dv;
      for (int off = 1; off < 64; off <<= 1) vv += __shfl_xor(vv, off);
      vv *= (1.f / 64.f);
      sx[rr * 68 + lc] = dv * rsqrtf(vv + 1e-5f) * g1[lc] + b1[lc];
    }
    stage_w<64, 128, 130>(w1, wls, t);
  }
  __syncthreads();
  {  // ffnh = relu(y @ w1) -> pool stride 128
    int rrk = t >> 7, ck = t & 127;
    float a0 = 0.f, a1 = 0.f, a2 = 0.f, a3 = 0.f;
#pragma unroll 8
    for (int k = 0; k < 64; k++) {
      float wv = (float)wls[k * 130 + ck];
      a0 += sx[rrk * 68 + k] * wv;
      a1 += sx[(rrk + 8) * 68 + k] * wv;
      a2 += sx[(rrk + 16) * 68 + k] * wv;
      a3 += sx[(rrk + 24) * 68 + k] * wv;
    }
    pool[rrk * 128 + ck] = fmaxf(a0, 0.f);
    pool[(rrk + 8) * 128 + ck] = fmaxf(a1, 0.f);
    pool[(rrk + 16) * 128 + ck] = fmaxf(a2, 0.f);
    pool[(rrk + 24) * 128 + ck] = fmaxf(a3, 0.f);
  }
  __syncthreads();
  stage_w<128, 64, 66>(w2, wls, t);
  __syncthreads();
  {  // z = y + ffnh @ w2 ; LN2 ; out
    int wv_ = t >> 6, lc = t & 63;
#pragma unroll
    for (int pass = 0; pass < 2; pass++) {
      int rr = wv_ + pass * 16;
      float ff = 0.f;
#pragma unroll 8
      for (int k = 0; k < 128; k++) ff += pool[rr * 128 + k] * (float)wls[k * 66 + lc];
      float z = sx[rr * 68 + lc] + ff;
      float m2 = z;
      for (int off = 1; off < 64; off <<= 1) m2 += __shfl_xor(m2, off);
      m2 *= (1.f / 64.f);
      float dz = z - m2, v2 = dz * dz;
      for (int off = 1; off < 64; off <<= 1) v2 += __shfl_xor(v2, off);
      v2 *= (1.f / 64.f);
      out[b * 2048 + rr * 64 + lc] = dz * rsqrtf(v2 + 1e-5f) * g2[lc] + b2v[lc];
    }
  }
}

// ---------------------------------------------------------------------------
extern "C" void kernel_launch(void* const* d_in, const int* in_sizes, int n_in,
                              void* d_out, int out_size, void* d_ws, size_t ws_size,
                              hipStream_t stream) {
  const float* h_in   = (const float*)d_in[0];
  const float* p_in   = (const float*)d_in[1];
  const float* e_in   = (const float*)d_in[2];
  const float* krw    = (const float*)d_in[3];
  const float* quer   = (const float*)d_in[4];
  const float* mask   = (const float*)d_in[5];
  const float* wq_p   = (const float*)d_in[6];
  const float* wk_p   = (const float*)d_in[7];
  const float* we_p   = (const float*)d_in[8];
  const float* wv_p   = (const float*)d_in[9];
  const float* wo_p   = (const float*)d_in[10];
  const float* cq_wq  = (const float*)d_in[11];
  const float* cq_wkv = (const float*)d_in[12];
  const float* cq_wo  = (const float*)d_in[13];
  const float* cq_bo  = (const float*)d_in[14];
  const float* sa_wq  = (const float*)d_in[15];
  const float* sa_wkv = (const float*)d_in[16];
  const float* sa_wo  = (const float*)d_in[17];
  const float* sa_bo  = (const float*)d_in[18];
  const float* oq_w   = (const float*)d_in[19];
  const float* ln1_g  = (const float*)d_in[20];
  const float* ln1_b  = (const float*)d_in[21];
  const float* ffn_w1 = (const float*)d_in[22];
  const float* ffn_w2 = (const float*)d_in[23];
  const float* ln2_g  = (const float*)d_in[24];
  const float* ln2_b  = (const float*)d_in[25];

  float* ws = (float*)d_ws;
  float* Q  = ws;              // 131072
  float* Ks = Q + 131072;      // 131072
  float* V  = Ks + 131072;     // 131072
  float* Kc = V + 131072;      // 131072
  float* Vc = Kc + 131072;     // 131072  total 2.6 MB

  k_proj<<<256, 256, 0, stream>>>(p_in, wq_p, wk_p, wv_p, Q, Ks, V);
  k_edge<<<2048, 256, 0, stream>>>(e_in, we_p, krw, mask, h_in, p_in, wo_p, cq_wkv,
                                   Q, Ks, V, Kc, Vc);
  k_tail<<<8, 1024, 0, stream>>>(quer, Kc, Vc, mask, cq_wq, cq_wo, cq_bo,
                                 sa_wq, sa_wkv, sa_wo, sa_bo, oq_w,
                                 ln1_g, ln1_b, ffn_w1, ffn_w2, ln2_g, ln2_b,
                                 (float*)d_out);
}

// Round 7
// 315.665 us; speedup vs baseline: 1.0963x; 1.0963x over previous
//
#include <hip/hip_runtime.h>
#include <hip/hip_bf16.h>
#include <math.h>

typedef __bf16 bf16x8 __attribute__((ext_vector_type(8)));
typedef float floatx4 __attribute__((ext_vector_type(4)));

#define ATT_SCALE 0.35355339059327373f  // DH^-0.5, DH=8

__device__ __forceinline__ __bf16 f2b(float x) { return (__bf16)x; }

// ---------------------------------------------------------------------------
// K1: blocks 0..255: Q/Ks/V = p@{wq,wk,wv} (8 rows/block).
//     blocks 256..287: q1 = queries@cq_wq (8 rows/block).
// grid 288 x 256
// ---------------------------------------------------------------------------
__global__ __launch_bounds__(256) void k_proj(const float* __restrict__ p,
                       const float* __restrict__ quer,
                       const float* __restrict__ wq, const float* __restrict__ wk,
                       const float* __restrict__ wv, const float* __restrict__ cq_wq,
                       float* __restrict__ Q, float* __restrict__ Ks,
                       float* __restrict__ V, float* __restrict__ q1) {
  int blk = blockIdx.x, t = threadIdx.x;
  __shared__ float xr[8][64];
  const float* src = (blk < 256) ? (p + blk * 512) : (quer + (blk - 256) * 512);
  {
    int rr = t >> 5, cc = (t & 31) * 2;
    float2 pz = *reinterpret_cast<const float2*>(src + rr * 64 + cc);
    xr[rr][cc] = pz.x; xr[rr][cc + 1] = pz.y;
  }
  __syncthreads();
  if (blk < 256) {
    if (t < 192) {
      int mat = t >> 6, c = t & 63;
      const float* w = (mat == 0) ? wq : ((mat == 1) ? wk : wv);
      float acc[8] = {0.f, 0.f, 0.f, 0.f, 0.f, 0.f, 0.f, 0.f};
#pragma unroll 8
      for (int k = 0; k < 64; k++) {
        float wv_ = w[k * 64 + c];
#pragma unroll
        for (int r = 0; r < 8; r++) acc[r] += xr[r][k] * wv_;
      }
      float* dst = (mat == 0) ? Q : ((mat == 1) ? Ks : V);
      float sc = (mat == 1) ? ATT_SCALE : 1.f;
#pragma unroll
      for (int r = 0; r < 8; r++) dst[(blk * 8 + r) * 64 + c] = acc[r] * sc;
    }
  } else {
    if (t < 64) {
      int c = t;
      float acc[8] = {0.f, 0.f, 0.f, 0.f, 0.f, 0.f, 0.f, 0.f};
#pragma unroll 8
      for (int k = 0; k < 64; k++) {
        float wv_ = cq_wq[k * 64 + c];
#pragma unroll
        for (int r = 0; r < 8; r++) acc[r] += xr[r][k] * wv_;
      }
#pragma unroll
      for (int r = 0; r < 8; r++) q1[((blk - 256) * 8 + r) * 64 + c] = acc[r];
    }
  }
}

// ---------------------------------------------------------------------------
// K2: edge attention — byte-identical to the round-2 version.
// ---------------------------------------------------------------------------
__global__ __launch_bounds__(256) void k_edge(
    const float* __restrict__ e, const float* __restrict__ we,
    const float* __restrict__ krw, const float* __restrict__ mask,
    const float* __restrict__ hin, const float* __restrict__ pin,
    const float* __restrict__ wo, const float* __restrict__ cq_wkv,
    const float* __restrict__ Q, const float* __restrict__ Ks,
    const float* __restrict__ V, float* __restrict__ Kc, float* __restrict__ Vc) {
  int bi = blockIdx.x;          // b*256 + i
  int b = bi >> 8;
  int t = threadIdx.x;
  int w = t >> 6, l = t & 63;
  int l15 = l & 15, quad = l >> 4, half8 = (l >> 3) & 1, d = l & 7;

  bf16x8 wfrag[4][2];
  for (int nt = 0; nt < 4; nt++)
    for (int kc = 0; kc < 2; kc++)
      for (int jj = 0; jj < 8; jj++)
        wfrag[nt][kc][jj] = f2b(we[(kc * 32 + quad * 8 + jj) * 64 + nt * 16 + l15]);

  float qv[4];
  for (int nt = 0; nt < 4; nt++) qv[nt] = Q[bi * 64 + nt * 16 + l15];
  float mi = mask[bi];

  float aout[4] = {0.f, 0.f, 0.f, 0.f};
  float aden[4] = {0.f, 0.f, 0.f, 0.f};

  for (int mt = 0; mt < 4; mt++) {
    int j0 = w * 64 + mt * 16;
    const float* ep = e + ((long)bi * 256 + j0 + l15) * 64 + quad * 8;
    float4 ea = *reinterpret_cast<const float4*>(ep);
    float4 eb4 = *reinterpret_cast<const float4*>(ep + 4);
    float4 ec = *reinterpret_cast<const float4*>(ep + 32);
    float4 ed4 = *reinterpret_cast<const float4*>(ep + 36);
    bf16x8 a0, a1;
    a0[0] = f2b(ea.x); a0[1] = f2b(ea.y); a0[2] = f2b(ea.z); a0[3] = f2b(ea.w);
    a0[4] = f2b(eb4.x); a0[5] = f2b(eb4.y); a0[6] = f2b(eb4.z); a0[7] = f2b(eb4.w);
    a1[0] = f2b(ec.x); a1[1] = f2b(ec.y); a1[2] = f2b(ec.z); a1[3] = f2b(ec.w);
    a1[4] = f2b(ed4.x); a1[5] = f2b(ed4.y); a1[6] = f2b(ed4.z); a1[7] = f2b(ed4.w);

    int jr0 = j0 + quad * 4;
    float krw_r[4], mj_r[4];
    for (int r = 0; r < 4; r++) {
      krw_r[r] = krw[(long)bi * 256 + jr0 + r];
      mj_r[r] = mask[b * 256 + jr0 + r];
    }
    for (int nt = 0; nt < 4; nt++) {
      floatx4 acc = {0.f, 0.f, 0.f, 0.f};
      acc = __builtin_amdgcn_mfma_f32_16x16x32_bf16(a0, wfrag[nt][0], acc, 0, 0, 0);
      acc = __builtin_amdgcn_mfma_f32_16x16x32_bf16(a1, wfrag[nt][1], acc, 0, 0, 0);
      int hk = nt * 16 + l15;
      int hbase = hk & 56;
      for (int r = 0; r < 4; r++) {
        int jr = jr0 + r;
        float s = acc[r] * qv[nt] * Ks[(b * 256 + jr) * 64 + hk];
        s += __shfl_xor(s, 1);
        s += __shfl_xor(s, 2);
        s += __shfl_xor(s, 4);
        float wg = __expf(s) * krw_r[r] * mj_r[r];
        aden[nt] += wg;
        aout[nt] += wg * V[(b * 256 + jr) * 64 + hbase + d];
      }
    }
  }
  for (int nt = 0; nt < 4; nt++) {
    float o = aout[nt], dn = aden[nt];
    o += __shfl_xor(o, 16); o += __shfl_xor(o, 32);
    dn += __shfl_xor(dn, 16); dn += __shfl_xor(dn, 32);
    aout[nt] = o; aden[nt] = dn;
  }

  __shared__ float red[4][64];
  __shared__ float redden[4][8];
  __shared__ float pav[64];
  __shared__ float hcl[64];
  if (l < 16) {
    for (int nt = 0; nt < 4; nt++) {
      int head = nt * 2 + half8;
      red[w][head * 8 + d] = aout[nt];
      if (d == 0) redden[w][head] = aden[nt];
    }
  }
  __syncthreads();
  if (t < 64) {
    int head = t >> 3;
    float num = red[0][t] + red[1][t] + red[2][t] + red[3][t];
    float den = redden[0][head] + redden[1][head] + redden[2][head] + redden[3][head];
    num *= mi;
    den = fmaxf(den * mi, 1e-6f);
    pav[t] = num / den;
  }
  __syncthreads();
  if (t < 64) {
    float a = 0.f;
    for (int c = 0; c < 64; c++) a += pav[c] * wo[c * 64 + t];
    hcl[t] = hin[bi * 64 + t] + pin[bi * 64 + t] + tanhf(a);
  }
  __syncthreads();
  if (t < 128) {
    float a = 0.f;
    for (int c = 0; c < 64; c++) a += hcl[c] * cq_wkv[c * 128 + t];
    if (t < 64) Kc[bi * 64 + t] = a;
    else        Vc[bi * 64 + t - 64] = a;
  }
}

// ---------------------------------------------------------------------------
// T2: perceiver cross-attn per (b,h). grid 64 x 256 (round-2 verbatim).
// ---------------------------------------------------------------------------
__global__ void k_cross(const float* __restrict__ q1, const float* __restrict__ Kc,
                        const float* __restrict__ Vc, const float* __restrict__ mask,
                        float* __restrict__ oc) {
  int bh = blockIdx.x, b = bh >> 3, h = bh & 7;
  int t = threadIdx.x, r = t >> 3, g = t & 7;
  __shared__ float qL[32][8];
  qL[r][g] = q1[(b * 32 + r) * 64 + h * 8 + g];
  __syncthreads();
  float num[8] = {0.f, 0.f, 0.f, 0.f, 0.f, 0.f, 0.f, 0.f};
  float den = 0.f;
  for (int jj = 0; jj < 32; jj++) {
    int j = jj * 8 + g;
    const float* kp = Kc + (b * 256 + j) * 64 + h * 8;
    float s = 0.f;
    for (int dd = 0; dd < 8; dd++) s += qL[r][dd] * kp[dd];
    s *= ATT_SCALE;
    float mj = mask[b * 256 + j];
    s = (mj > 0.5f) ? s : -1e30f;
    s = fminf(fmaxf(s, -5.f), 5.f);
    float ex = __expf(s);
    den += ex;
    const float* vp = Vc + (b * 256 + j) * 64 + h * 8;
    for (int dd = 0; dd < 8; dd++) num[dd] += ex * vp[dd];
  }
  den += __shfl_xor(den, 1); den += __shfl_xor(den, 2); den += __shfl_xor(den, 4);
  for (int dd = 0; dd < 8; dd++) {
    float v = num[dd];
    v += __shfl_xor(v, 1); v += __shfl_xor(v, 2); v += __shfl_xor(v, 4);
    num[dd] = v;
  }
  oc[(b * 32 + r) * 64 + h * 8 + g] = num[g] / den;
}

// ---------------------------------------------------------------------------
// TA: q_out = resid + attn_in@Wo + bo ; qq = q_out@wql ; kv = q_out@wkvl
// grid 256 x 64 (round-2 verbatim)
// ---------------------------------------------------------------------------
__global__ void k_projqkv(const float* __restrict__ attn_in, const float* __restrict__ Wo,
                          const float* __restrict__ bo, const float* __restrict__ residp,
                          const float* __restrict__ wql, const float* __restrict__ wkvl,
                          float* __restrict__ q_out, float* __restrict__ qq,
                          float* __restrict__ kvb) {
  int r = blockIdx.x, t = threadIdx.x;
  __shared__ float oL[64];
  __shared__ float qL[64];
  oL[t] = attn_in[r * 64 + t];
  __syncthreads();
  float a = 0.f;
  for (int c = 0; c < 64; c++) a += oL[c] * Wo[c * 64 + t];
  float qvv = residp[r * 64 + t] + a + bo[t];
  q_out[r * 64 + t] = qvv;
  qL[t] = qvv;
  __syncthreads();
  float aq = 0.f, ak = 0.f, av = 0.f;
  for (int c = 0; c < 64; c++) {
    float x = qL[c];
    aq += x * wql[c * 64 + t];
    ak += x * wkvl[c * 128 + t];
    av += x * wkvl[c * 128 + 64 + t];
  }
  qq[r * 64 + t] = aq;
  kvb[r * 128 + t] = ak;
  kvb[r * 128 + 64 + t] = av;
}

// ---------------------------------------------------------------------------
// T4: latent self-attn per (b,h), 32 keys. grid 64 x 256 (round-2 verbatim)
// ---------------------------------------------------------------------------
__global__ void k_sattn(const float* __restrict__ qq, const float* __restrict__ kvb,
                        float* __restrict__ os) {
  int bh = blockIdx.x, b = bh >> 3, h = bh & 7;
  int t = threadIdx.x, r = t >> 3, g = t & 7;
  __shared__ float qL[32][8];
  qL[r][g] = qq[(b * 32 + r) * 64 + h * 8 + g];
  __syncthreads();
  float num[8] = {0.f, 0.f, 0.f, 0.f, 0.f, 0.f, 0.f, 0.f};
  float den = 0.f;
  for (int jj = 0; jj < 4; jj++) {
    int j = jj * 8 + g;
    const float* kp = kvb + (b * 32 + j) * 128 + h * 8;
    float s = 0.f;
    for (int dd = 0; dd < 8; dd++) s += qL[r][dd] * kp[dd];
    s *= ATT_SCALE;
    s = fminf(fmaxf(s, -5.f), 5.f);
    float ex = __expf(s);
    den += ex;
    for (int dd = 0; dd < 8; dd++) num[dd] += ex * kp[64 + dd];
  }
  den += __shfl_xor(den, 1); den += __shfl_xor(den, 2); den += __shfl_xor(den, 4);
  for (int dd = 0; dd < 8; dd++) {
    float v = num[dd];
    v += __shfl_xor(v, 1); v += __shfl_xor(v, 2); v += __shfl_xor(v, 4);
    num[dd] = v;
  }
  os[(b * 32 + r) * 64 + h * 8 + g] = num[g] / den;
}

// ---------------------------------------------------------------------------
// TB: final: q2 = qprev + os@Wo + bo ; x=q2@oq_w ; LN1 ; ffn ; LN2 -> out
// grid 256 x 64 (round-2 verbatim)
// ---------------------------------------------------------------------------
__global__ void k_final(const float* __restrict__ os, const float* __restrict__ Wo,
                        const float* __restrict__ bo, const float* __restrict__ qprev,
                        const float* __restrict__ oqw, const float* __restrict__ g1,
                        const float* __restrict__ b1, const float* __restrict__ w1,
                        const float* __restrict__ w2, const float* __restrict__ g2,
                        const float* __restrict__ b2v, float* __restrict__ out) {
  int r = blockIdx.x, t = threadIdx.x;
  __shared__ float oL[64];
  __shared__ float q2L[64];
  __shared__ float yL[64];
  __shared__ float hhs[128];
  oL[t] = os[r * 64 + t];
  __syncthreads();
  float a = 0.f;
  for (int c = 0; c < 64; c++) a += oL[c] * Wo[c * 64 + t];
  float q2 = qprev[r * 64 + t] + a + bo[t];
  q2L[t] = q2;
  __syncthreads();
  float x = 0.f;
  for (int c = 0; c < 64; c++) x += q2L[c] * oqw[c * 64 + t];
  float m = x;
  for (int off = 1; off < 64; off <<= 1) m += __shfl_xor(m, off);
  m *= (1.f / 64.f);
  float dv = x - m, vv = dv * dv;
  for (int off = 1; off < 64; off <<= 1) vv += __shfl_xor(vv, off);
  vv *= (1.f / 64.f);
  float y = dv * rsqrtf(vv + 1e-5f) * g1[t] + b1[t];
  yL[t] = y;
  __syncthreads();
  float h1 = 0.f, h2 = 0.f;
  for (int c = 0; c < 64; c++) {
    float xx = yL[c];
    h1 += xx * w1[c * 128 + t];
    h2 += xx * w1[c * 128 + 64 + t];
  }
  hhs[t] = fmaxf(h1, 0.f);
  hhs[t + 64] = fmaxf(h2, 0.f);
  __syncthreads();
  float ff = 0.f;
  for (int c = 0; c < 128; c++) ff += hhs[c] * w2[c * 64 + t];
  float z = y + ff;
  float m2 = z;
  for (int off = 1; off < 64; off <<= 1) m2 += __shfl_xor(m2, off);
  m2 *= (1.f / 64.f);
  float dz = z - m2, v2 = dz * dz;
  for (int off = 1; off < 64; off <<= 1) v2 += __shfl_xor(v2, off);
  v2 *= (1.f / 64.f);
  float z2 = dz * rsqrtf(v2 + 1e-5f) * g2[t] + b2v[t];
  out[r * 64 + t] = z2;
}

// ---------------------------------------------------------------------------
extern "C" void kernel_launch(void* const* d_in, const int* in_sizes, int n_in,
                              void* d_out, int out_size, void* d_ws, size_t ws_size,
                              hipStream_t stream) {
  const float* h_in   = (const float*)d_in[0];
  const float* p_in   = (const float*)d_in[1];
  const float* e_in   = (const float*)d_in[2];
  const float* krw    = (const float*)d_in[3];
  const float* quer   = (const float*)d_in[4];
  const float* mask   = (const float*)d_in[5];
  const float* wq_p   = (const float*)d_in[6];
  const float* wk_p   = (const float*)d_in[7];
  const float* we_p   = (const float*)d_in[8];
  const float* wv_p   = (const float*)d_in[9];
  const float* wo_p   = (const float*)d_in[10];
  const float* cq_wq  = (const float*)d_in[11];
  const float* cq_wkv = (const float*)d_in[12];
  const float* cq_wo  = (const float*)d_in[13];
  const float* cq_bo  = (const float*)d_in[14];
  const float* sa_wq  = (const float*)d_in[15];
  const float* sa_wkv = (const float*)d_in[16];
  const float* sa_wo  = (const float*)d_in[17];
  const float* sa_bo  = (const float*)d_in[18];
  const float* oq_w   = (const float*)d_in[19];
  const float* ln1_g  = (const float*)d_in[20];
  const float* ln1_b  = (const float*)d_in[21];
  const float* ffn_w1 = (const float*)d_in[22];
  const float* ffn_w2 = (const float*)d_in[23];
  const float* ln2_g  = (const float*)d_in[24];
  const float* ln2_b  = (const float*)d_in[25];

  float* ws = (float*)d_ws;
  float* Q   = ws;              // 131072
  float* Ks  = Q + 131072;      // 131072
  float* V   = Ks + 131072;     // 131072
  float* q1  = V + 131072;      // 16384
  float* Kc  = q1 + 16384;      // 131072
  float* Vc  = Kc + 131072;     // 131072
  float* oc  = Vc + 131072;     // 16384
  float* q0  = oc + 16384;      // 16384
  float* qq  = q0 + 16384;      // 16384
  float* kvb = qq + 16384;      // 32768
  float* osa = kvb + 32768;     // 16384
  float* qc1 = osa + 16384;     // 16384   total ~3.1 MB

  k_proj<<<288, 256, 0, stream>>>(p_in, quer, wq_p, wk_p, wv_p, cq_wq, Q, Ks, V, q1);
  k_edge<<<2048, 256, 0, stream>>>(e_in, we_p, krw, mask, h_in, p_in, wo_p, cq_wkv,
                                   Q, Ks, V, Kc, Vc);
  k_cross<<<64, 256, 0, stream>>>(q1, Kc, Vc, mask, oc);
  k_projqkv<<<256, 64, 0, stream>>>(oc, cq_wo, cq_bo, quer,
                                    sa_wq, sa_wkv, q0, qq, kvb);
  k_sattn<<<64, 256, 0, stream>>>(qq, kvb, osa);
  k_projqkv<<<256, 64, 0, stream>>>(osa, sa_wo, sa_bo, q0,
                                    sa_wq + 4096, sa_wkv + 8192, qc1, qq, kvb);
  k_sattn<<<64, 256, 0, stream>>>(qq, kvb, osa);
  k_final<<<256, 64, 0, stream>>>(osa, sa_wo + 4096, sa_bo + 64, qc1, oq_w,
                                  ln1_g, ln1_b, ffn_w1, ffn_w2, ln2_g, ln2_b,
                                  (float*)d_out);
}